// Round 1
// baseline (394.014 us; speedup 1.0000x reference)
//
#include <hip/hip_runtime.h>
#include <stdint.h>

typedef unsigned short ushort_t;
typedef unsigned int uint_t;

#define B_SZ 16
#define CIN 64
#define COUT 64
#define N_SZ 1024
#define L_SZ 12
#define CL 768            // COUT * L_SZ
#define NL 12288          // N_SZ * L_SZ
#define PT 96             // conv positions per block = 8 whole n rows
#define ALPHA 0.2f

typedef __bf16 bf16x8 __attribute__((ext_vector_type(8)));
typedef float floatx4 __attribute__((ext_vector_type(4)));
typedef _Float16 half8 __attribute__((ext_vector_type(8)));
typedef _Float16 half4 __attribute__((ext_vector_type(4)));

__device__ __forceinline__ ushort_t f2bf(float x) {
    uint_t u = __float_as_uint(x);
    u += 0x7fffu + ((u >> 16) & 1u);
    return (ushort_t)(u >> 16);
}
__device__ __forceinline__ float bf2f(ushort_t h) {
    return __uint_as_float(((uint_t)h) << 16);
}

// async global->LDS, 16B per lane; LDS dest must be wave-uniform base + lane*16
#define ASYNC16(ldsp, gp)                                                \
    __builtin_amdgcn_global_load_lds(                                    \
        (const __attribute__((address_space(1))) void*)(gp),             \
        (__attribute__((address_space(3))) void*)(ldsp), 16, 0, 0)

// ---------------------------------------------------------------------------
// K1: conv0 (1x3, pad 1) + bias + fused f, as an f16 MFMA im2col GEMM.
//   x[co][p=(n,l)] = sum_{k=(kt,ci)} A[co][k] * B[k][p],  K = 192.
// Block = one batch b, PT=96 positions (8 whole n => zero-pad never crosses
// the tile; no halo). B-tile built in LDS at stage time: each input elem is
// written to its 3 kt-slots with l-boundary slots forced to ZERO; every slot
// written exactly once. A-frags loaded per-lane from global (w0 is 48KB,
// L2-hot). f16 operands (2^-11 rounding) keep conv error ~4e-4 (vs 6e-3 for
// bf16) so absmax is unchanged. One block covers all 64 co for its 8 n =>
// exact f per block, no atomics, no memset.
// LDS 38.8KB -> 4 blocks/CU. Grid (NL/PT=128, B) = 2048 blocks.
// ---------------------------------------------------------------------------
__global__ __launch_bounds__(256, 4) void conv_mfma_kernel(
    const float* __restrict__ inp, const float* __restrict__ w0,
    const float* __restrict__ b0, const float* __restrict__ w1,
    ushort_t* __restrict__ Xt, float* __restrict__ fout)
{
    __shared__ _Float16 Bs[PT * 200];   // [p][k 0..191, pad to 200] 38400 B
    __shared__ float fredcol[PT];

    const int bx = blockIdx.x;          // position tile (8 n)
    const int b  = blockIdx.y;
    const int t  = threadIdx.x;
    const int lane = t & 63, w = t >> 6;     // w = co-tile of this wave
    const int rr = lane & 15, kc = lane >> 4;
    const int p0 = bx * PT;

    if (t < PT) fredcol[t] = 0.f;

    // ---- stage im2col B-tile: 16 ci-groups x 96 p tasks, 6 per thread ----
    const float* ibase = inp + (size_t)b * CIN * NL;
    const half4 hz = (half4)(_Float16)0.f;
#pragma unroll
    for (int i = 0; i < 6; i++) {
        const int idx = i * 256 + t;
        const int p = idx % PT;
        const int cig = idx / PT;
        const int pg = p0 + p;
        const int l = pg % 12;
        const float* src = ibase + (size_t)(cig * 4) * NL + pg;
        half4 hv;
        hv[0] = (_Float16)src[0];
        hv[1] = (_Float16)src[NL];
        hv[2] = (_Float16)src[2 * NL];
        hv[3] = (_Float16)src[3 * NL];
        // kt=1: B[64+ci][p] = in[ci][p]
        *(half4*)&Bs[p * 200 + 64 + cig * 4] = hv;
        // kt=0: B[ci][p+1] = in[ci][p], zero when it would cross an n row
        if (p + 1 < PT) {
            half4 v0 = hv; if (l == 11) v0 = hz;
            *(half4*)&Bs[(p + 1) * 200 + cig * 4] = v0;
        }
        // kt=2: B[128+ci][p-1] = in[ci][p], zero when it would cross an n row
        if (p >= 1) {
            half4 v2 = hv; if (l == 0) v2 = hz;
            *(half4*)&Bs[(p - 1) * 200 + 128 + cig * 4] = v2;
        }
    }
    // tile-edge padding columns (always exactly zero)
    if (t < 16) *(half4*)&Bs[0 * 200 + t * 4] = hz;                  // kt=0, c=0
    else if (t < 32) *(half4*)&Bs[95 * 200 + 128 + (t - 16) * 4] = hz; // kt=2, c=95

    // ---- A fragments from global (L2-hot), overlap with ds writes ----
    const int co_r = w * 16 + rr;
    half8 af[6];
#pragma unroll
    for (int ch = 0; ch < 6; ch++) {
        const int kt = ch >> 1;
        const int ci0 = (ch & 1) * 32 + kc * 8;
        const float* wp = w0 + co_r * 192 + ci0 * 3 + kt;
#pragma unroll
        for (int e = 0; e < 8; e++) af[ch][e] = (_Float16)wp[e * 3];
    }

    __syncthreads();

    // ---- MFMA: 6 p-frags x 6 k-chunks per wave ----
    floatx4 acc[6];
#pragma unroll
    for (int fp = 0; fp < 6; fp++) acc[fp] = (floatx4)0.f;
#pragma unroll
    for (int fp = 0; fp < 6; fp++) {
        const _Float16* brow = &Bs[(fp * 16 + rr) * 200 + kc * 8];
#pragma unroll
        for (int ch = 0; ch < 6; ch++) {
            const half8 bf = *(const half8*)(brow + ch * 32);
            acc[fp] = __builtin_amdgcn_mfma_f32_16x16x32_f16(af[ch], bf, acc[fp], 0, 0, 0);
        }
    }

    // ---- epilogue: bias, Xt bf16 store, exact per-block f ----
    float b0v[4];
#pragma unroll
    for (int r = 0; r < 4; r++) b0v[r] = b0[w * 16 + kc * 4 + r];

    ushort_t* XtB = Xt + (size_t)b * CL * N_SZ;
#pragma unroll
    for (int fp = 0; fp < 6; fp++) {
        const int pcol = fp * 16 + rr;
        const int pg = p0 + pcol;
        const int n = pg / 12;
        const int l = pg - n * 12;
        float fc = 0.f;
#pragma unroll
        for (int r = 0; r < 4; r++) {
            const int co = w * 16 + kc * 4 + r;
            const float x = acc[fp][r] + b0v[r];
            fc += x * w1[co * 12 + l];
            XtB[(size_t)(co * 12 + l) * N_SZ + n] = f2bf(x);
        }
        atomicAdd(&fredcol[pcol], fc);
    }
    __syncthreads();
    if (t < 8) {
        float s = 0.f;
#pragma unroll
        for (int j = 0; j < 12; j++) s += fredcol[t * 12 + j];
        fout[b * N_SZ + bx * 8 + t] = s;
    }
}

// ---------------------------------------------------------------------------
// K2: z = leaky(f_i + f_j) + adj; row softmax; store S bf16 (row-major).
// Block: 256 thr per row; grid (N, B).
// ---------------------------------------------------------------------------
__global__ __launch_bounds__(256) void softmax_kernel(
    const float* __restrict__ adj, const float* __restrict__ f,
    ushort_t* __restrict__ Sb)
{
    __shared__ float smx[4], sms[4];
    const int i = blockIdx.x, b = blockIdx.y, t = threadIdx.x;
    const int lane = t & 63, wv = t >> 6;

    const float* frow = f + b * N_SZ;
    const float fi = frow[i];
    const float4 fj = *(const float4*)(frow + 4 * t);
    const float4 av = *(const float4*)(adj + ((size_t)b * N_SZ + i) * N_SZ + 4 * t);

    float z[4];
    z[0] = fi + fj.x; z[1] = fi + fj.y; z[2] = fi + fj.z; z[3] = fi + fj.w;
#pragma unroll
    for (int k = 0; k < 4; k++) z[k] = (z[k] >= 0.f) ? z[k] : ALPHA * z[k];
    z[0] += av.x; z[1] += av.y; z[2] += av.z; z[3] += av.w;

    float mx = fmaxf(fmaxf(z[0], z[1]), fmaxf(z[2], z[3]));
#pragma unroll
    for (int o = 32; o; o >>= 1) mx = fmaxf(mx, __shfl_xor(mx, o, 64));
    if (lane == 0) smx[wv] = mx;
    __syncthreads();
    mx = fmaxf(fmaxf(smx[0], smx[1]), fmaxf(smx[2], smx[3]));

    float e[4], s = 0.f;
#pragma unroll
    for (int k = 0; k < 4; k++) { e[k] = __expf(z[k] - mx); s += e[k]; }
#pragma unroll
    for (int o = 32; o; o >>= 1) s += __shfl_xor(s, o, 64);
    if (lane == 0) sms[wv] = s;
    __syncthreads();
    s = sms[0] + sms[1] + sms[2] + sms[3];
    const float inv = 1.0f / s;

    const uint_t p0 = (uint_t)f2bf(e[0] * inv) | ((uint_t)f2bf(e[1] * inv) << 16);
    const uint_t p1 = (uint_t)f2bf(e[2] * inv) | ((uint_t)f2bf(e[3] * inv) << 16);
    uint2 pk; pk.x = p0; pk.y = p1;
    *(uint2*)&Sb[((size_t)b * N_SZ + i) * N_SZ + 4 * t] = pk;
}

// ---------------------------------------------------------------------------
// K3: attention output = S^T, bf16 -> fp32, LDS 64x64 tile transpose.
// grid (N/64, N/64, B): x = i-tile, y = j-tile.
// ---------------------------------------------------------------------------
__global__ __launch_bounds__(256) void att_transpose_kernel(
    const ushort_t* __restrict__ Sb, float* __restrict__ att)
{
    __shared__ float T[64][65];
    const int b = blockIdx.z;
    const int i0 = blockIdx.x * 64, j0 = blockIdx.y * 64;
    const int t = threadIdx.x;

#pragma unroll
    for (int ph = 0; ph < 2; ph++) {
        const int idx = ph * 256 + t;
        const int r = idx >> 3, c8 = (idx & 7) * 8;
        const uint4 v = *(const uint4*)(Sb + ((size_t)b * N_SZ + i0 + r) * N_SZ + j0 + c8);
        T[r][c8 + 0] = bf2f((ushort_t)(v.x & 0xffff));
        T[r][c8 + 1] = bf2f((ushort_t)(v.x >> 16));
        T[r][c8 + 2] = bf2f((ushort_t)(v.y & 0xffff));
        T[r][c8 + 3] = bf2f((ushort_t)(v.y >> 16));
        T[r][c8 + 4] = bf2f((ushort_t)(v.z & 0xffff));
        T[r][c8 + 5] = bf2f((ushort_t)(v.z >> 16));
        T[r][c8 + 6] = bf2f((ushort_t)(v.w & 0xffff));
        T[r][c8 + 7] = bf2f((ushort_t)(v.w >> 16));
    }
    __syncthreads();
#pragma unroll
    for (int ph = 0; ph < 4; ph++) {
        const int idx = ph * 256 + t;
        const int jr = idx >> 4, i4 = (idx & 15) * 4;
        float4 o;
        o.x = T[i4 + 0][jr]; o.y = T[i4 + 1][jr];
        o.z = T[i4 + 2][jr]; o.w = T[i4 + 3][jr];
        *(float4*)(att + ((size_t)b * N_SZ + j0 + jr) * N_SZ + i0 + i4) = o;
    }
}

// ---------------------------------------------------------------------------
// K4: per-batch GEMM  C[q,m] = sum_n S[q,n] * Xt[m,n], m=(co*12+l).
// 128x128 block tile, BK=64 (the proven m97 config: halves barrier count vs
// BK=32), 4 waves in 2x2, each wave 64x64 via 4x4 mfma_f32_16x16x32_bf16.
// Staging via global_load_lds width=16. LDS 32KB. Epilogue scatters into
// NCHW out. grid (CL/128=6, N/128=8, B).
// ---------------------------------------------------------------------------
__global__ __launch_bounds__(256) void gemm2_kernel(
    const ushort_t* __restrict__ Sb, const ushort_t* __restrict__ Xt,
    float* __restrict__ out)
{
    __shared__ ushort_t As[1024 * 8];
    __shared__ ushort_t Bs[1024 * 8];
    const int b = blockIdx.z;
    const int m0 = blockIdx.x * 128, q0 = blockIdx.y * 128;
    const int t = threadIdx.x;
    const int lane = t & 63, wv = t >> 6;
    const int wq = wv >> 1, wm = wv & 1;
    const int kc = lane >> 4, rr = lane & 15;

    const ushort_t* Sbase = Sb + (size_t)b * N_SZ * N_SZ;
    const ushort_t* Xbase = Xt + (size_t)b * CL * N_SZ;

    floatx4 acc[4][4];
#pragma unroll
    for (int i = 0; i < 4; i++)
#pragma unroll
        for (int j = 0; j < 4; j++) acc[i][j] = (floatx4)0.f;

    for (int k0 = 0; k0 < N_SZ; k0 += 64) {
        __syncthreads();
#pragma unroll
        for (int c = 0; c < 4; c++) {
            const int u = c * 256 + t;
            const int r = u & 127, kcs = u >> 7;
            ASYNC16(&As[u * 8], Sbase + (size_t)(q0 + r) * N_SZ + k0 + kcs * 8);
            ASYNC16(&Bs[u * 8], Xbase + (size_t)(m0 + r) * N_SZ + k0 + kcs * 8);
        }
        __syncthreads();

#pragma unroll
        for (int kk = 0; kk < 2; kk++) {
            bf16x8 af[4], bfr[4];
#pragma unroll
            for (int i = 0; i < 4; i++) {
                af[i]  = *(const bf16x8*)&As[((kk * 4 + kc) * 128 + wq * 64 + i * 16 + rr) * 8];
                bfr[i] = *(const bf16x8*)&Bs[((kk * 4 + kc) * 128 + wm * 64 + i * 16 + rr) * 8];
            }
#pragma unroll
            for (int i = 0; i < 4; i++)
#pragma unroll
                for (int j = 0; j < 4; j++)
                    acc[i][j] = __builtin_amdgcn_mfma_f32_16x16x32_bf16(
                        af[i], bfr[j], acc[i][j], 0, 0, 0);
        }
    }

    // epilogue: C row = q (= kc*4 + reg within frag), col = m (= rr within frag)
#pragma unroll
    for (int j = 0; j < 4; j++) {
        const int m = m0 + wm * 64 + j * 16 + rr;
        const int co = m / 12, l = m - co * 12;
        float* ob = out + (size_t)(b * COUT + co) * (N_SZ * L_SZ) + l;
#pragma unroll
        for (int i = 0; i < 4; i++) {
            const int q = q0 + wq * 64 + i * 16 + kc * 4;
#pragma unroll
            for (int r2 = 0; r2 < 4; r2++)
                ob[(size_t)(q + r2) * 12] = acc[i][j][r2];
        }
    }
}

// ---------------------------------------------------------------------------
extern "C" void kernel_launch(void* const* d_in, const int* in_sizes, int n_in,
                              void* d_out, int out_size, void* d_ws, size_t ws_size,
                              hipStream_t stream)
{
    const float* inp = (const float*)d_in[0];
    const float* adj = (const float*)d_in[1];
    const float* w0  = (const float*)d_in[2];
    const float* b0  = (const float*)d_in[3];
    const float* w1  = (const float*)d_in[4];

    float* hprime = (float*)d_out;                       // 16*64*1024*12
    float* att    = hprime + (size_t)B_SZ * COUT * N_SZ * L_SZ;

    char* ws = (char*)d_ws;
    ushort_t* Xt = (ushort_t*)ws;                              // 25,165,824 B
    ushort_t* Sb = (ushort_t*)(ws + (size_t)25165824);         // 33,554,432 B
    float*    fw = (float*)(ws + (size_t)25165824 + 33554432); //     65,536 B

    conv_mfma_kernel<<<dim3(NL / PT, B_SZ), 256, 0, stream>>>(inp, w0, b0, w1, Xt, fw);
    softmax_kernel<<<dim3(N_SZ, B_SZ), 256, 0, stream>>>(adj, fw, Sb);
    att_transpose_kernel<<<dim3(N_SZ / 64, N_SZ / 64, B_SZ), 256, 0, stream>>>(Sb, att);
    gemm2_kernel<<<dim3(CL / 128, N_SZ / 128, B_SZ), 256, 0, stream>>>(Sb, Xt, hprime);
}